// Round 7
// baseline (92.022 us; speedup 1.0000x reference)
//
#include <hip/hip_runtime.h>
#include <stdint.h>

typedef __bf16 bf16x8 __attribute__((ext_vector_type(8)));
typedef float f32x4 __attribute__((ext_vector_type(4)));
typedef __attribute__((address_space(3))) uint32_t as3u32;
typedef const __attribute__((address_space(1))) uint32_t as1u32;

#define B_TOT 8192
#define DD 128
#define OUT_TOT 67108864UL
#define OUT_AVG 67117056UL

__device__ inline unsigned short f2bf(float x){
  union { float f; uint32_t u; } v; v.f = x;
  return (unsigned short)((v.u + 0x7fffu + ((v.u >> 16) & 1u)) >> 16);
}

// ---------------- phase 1: gather + normalize + h + pos (+ zero accumulators) ----
__device__ inline float bsum128(float v, volatile float* s2){
  #pragma unroll
  for (int o = 32; o; o >>= 1) v += __shfl_xor(v, o);
  __syncthreads();
  if ((threadIdx.x & 63) == 0) s2[threadIdx.x >> 6] = v;
  __syncthreads();
  return s2[0] + s2[1];
}

__global__ __launch_bounds__(128) void k_feat(const float* __restrict__ x1,
    const float* __restrict__ x2, const int* __restrict__ i1a, const int* __restrict__ i2a,
    unsigned short* __restrict__ f1b, unsigned short* __restrict__ f2b,
    unsigned short* __restrict__ hb, float* __restrict__ posw, float* __restrict__ out){
  __shared__ float s2[2];
  int b = blockIdx.x, t = threadIdx.x;
  int gid = b * 128 + t;
  if (gid <= 8192) out[OUT_TOT + gid] = 0.f;   // zero tot_rating accum + avg slot
  size_t r1 = (size_t)i1a[b] * DD, r2 = (size_t)i2a[b] * DD;
  float v1 = x1[r1 + t], v2 = x2[r2 + t];
  float n1 = sqrtf(bsum128(v1 * v1, s2));
  float f1 = v1 / fmaxf(n1, 1e-12f);
  float n2 = sqrtf(bsum128(v2 * v2, s2));
  float f2 = v2 / fmaxf(n2, 1e-12f);
  float h = f1 * f2;
  float pos = bsum128(h, s2);
  int o = b * DD + t;
  f1b[o] = f2bf(f1); f2b[o] = f2bf(f2); hb[o] = f2bf(h);
  if (t == 0) posw[b] = pos;
}

// ---------------- shared staging (128x128 bf16 tile, XOR-swizzled) ----------------
// LDS chunk (row, cc) holds global chunk (row, cc ^ (row&7)); global_load_lds
// writes LDS linearly -> pre-swizzle the per-lane GLOBAL source (rule #21).
__device__ inline void stage_tile(const unsigned short* g, unsigned short* s){
  int tid = threadIdx.x;
  #pragma unroll
  for (int it = 0; it < 8; ++it){
    int c = tid + it * 256;          // 2048 chunks of 16B
    int row = c >> 4, cc = c & 15;
    int src = (row << 4) + (cc ^ (row & 7));
    __builtin_amdgcn_global_load_lds((as1u32*)(g + src * 8),
                                     (as3u32*)(s + c * 8), 16, 0, 0);
  }
}

// A-frag: row = lane&15, k = 8*(lane>>4)+e. C/D: col = lane&15, row=(lane>>4)*4+reg.
__device__ inline void mfma_tile(const unsigned short* As, const unsigned short* Bs,
                                 f32x4 acc[4][4]){
  int tid = threadIdx.x;
  int w = tid >> 6, l = tid & 63;
  int wr = (w >> 1) * 64, wc = (w & 1) * 64;
  int lo = l & 15, hi = l >> 4;
  f32x4 zero = {0.f, 0.f, 0.f, 0.f};
  #pragma unroll
  for (int m = 0; m < 4; ++m)
    #pragma unroll
    for (int n = 0; n < 4; ++n) acc[m][n] = zero;
  #pragma unroll
  for (int kk = 0; kk < 4; ++kk){
    bf16x8 af[4], bfv[4];
    #pragma unroll
    for (int m = 0; m < 4; ++m){
      int row = wr + m * 16 + lo;
      af[m] = *(const bf16x8*)(As + row * 128 + ((kk * 4 + hi) ^ (row & 7)) * 8);
    }
    #pragma unroll
    for (int n = 0; n < 4; ++n){
      int row = wc + n * 16 + lo;
      bfv[n] = *(const bf16x8*)(Bs + row * 128 + ((kk * 4 + hi) ^ (row & 7)) * 8);
    }
    #pragma unroll
    for (int m = 0; m < 4; ++m)
      #pragma unroll
      for (int n = 0; n < 4; ++n)
        acc[m][n] = __builtin_amdgcn_mfma_f32_16x16x32_bf16(af[m], bfv[n], acc[m][n], 0, 0, 0);
  }
}

// ---------------- phase 2: lin1 + leaky + lin2 + sigmoid -> rT, temp-mean -------
__global__ __launch_bounds__(256) void k_lin(const unsigned short* __restrict__ hb,
    const float* __restrict__ W1, const float* __restrict__ b1,
    const float* __restrict__ W2, const float* __restrict__ b2,
    float* __restrict__ rTw, float* __restrict__ out){
  __shared__ __align__(16) unsigned short As[16384];
  __shared__ __align__(16) unsigned short Bs[16384];
  __shared__ float zpart[2][128];
  __shared__ float s4[4];
  int i0 = blockIdx.x * 128;
  int tid = threadIdx.x;
  stage_tile(hb + (size_t)i0 * 128, As);
  #pragma unroll
  for (int it = 0; it < 8; ++it){
    int c = tid + it * 256;
    int row = c >> 4, cc = c & 15;
    int src = (row << 4) + (cc ^ (row & 7));
    const float4* g4 = (const float4*)(W1 + src * 8);
    float4 a = g4[0], b = g4[1];
    unsigned short t8[8];
    t8[0] = f2bf(a.x); t8[1] = f2bf(a.y); t8[2] = f2bf(a.z); t8[3] = f2bf(a.w);
    t8[4] = f2bf(b.x); t8[5] = f2bf(b.y); t8[6] = f2bf(b.z); t8[7] = f2bf(b.w);
    *(uint4*)(Bs + c * 8) = *(uint4*)t8;
  }
  asm volatile("s_waitcnt vmcnt(0)" ::: "memory");
  __syncthreads();
  f32x4 acc[4][4];
  mfma_tile(As, Bs, acc);
  int w = tid >> 6, l = tid & 63;
  int wrb = (w >> 1) * 64, wcb = (w & 1) * 64, lo = l & 15, hi = l >> 4;
  float w2v[4], b1v[4];
  #pragma unroll
  for (int n = 0; n < 4; ++n){ int col = wcb + n * 16 + lo; w2v[n] = W2[col]; b1v[n] = b1[col]; }
  #pragma unroll
  for (int m = 0; m < 4; ++m){
    #pragma unroll
    for (int q = 0; q < 4; ++q){
      float p = 0.f;
      #pragma unroll
      for (int n = 0; n < 4; ++n){
        float hv = acc[m][n][q] + b1v[n];
        hv = hv >= 0.f ? hv : 0.2f * hv;   // leaky_relu(0.2)
        p += hv * w2v[n];
      }
      p += __shfl_xor(p, 1); p += __shfl_xor(p, 2);
      p += __shfl_xor(p, 4); p += __shfl_xor(p, 8);
      if (lo == 0) zpart[w & 1][wrb + m * 16 + hi * 4 + q] = p;
    }
  }
  __syncthreads();
  float Tloc = 0.f;
  if (tid < 128){
    float z = zpart[0][tid] + zpart[1][tid] + b2[0];
    float s = 1.f / (1.f + __expf(-z));
    float T = 0.95f * (1.f - s) + 0.05f;
    rTw[i0 + tid] = 1.f / T;
    Tloc = T;
  }
  float v = Tloc;
  #pragma unroll
  for (int o = 32; o; o >>= 1) v += __shfl_xor(v, o);
  if ((tid & 63) == 0) s4[tid >> 6] = v;
  __syncthreads();
  if (tid == 0) atomicAdd(out + OUT_AVG, (s4[0] + s4[1] + s4[2] + s4[3]) * (1.0f / 8192.0f));
}

// ------- phase 3: persistent-tile tot GEMM + pos writer, counted-vmcnt pipeline --
// Loop contains NO vmem ops except: 8 stage loads (issued first) then 16 nt-stores.
// s_waitcnt vmcnt(16) waits exactly for the loads; stores stay in flight across
// the barrier -> write pipe never drains to empty (T3/T4).
__global__ __launch_bounds__(256, 2) void k_tot(const unsigned short* __restrict__ f1b,
    const unsigned short* __restrict__ f2b, const float* __restrict__ rTw,
    const float* __restrict__ posw, float* __restrict__ out){
  __shared__ __align__(16) unsigned short Buf[16384];   // 32 KB
  __shared__ __align__(16) float posS[1024];            // 8 tiles x 128 pos
  __shared__ __align__(16) float rS[128];
  // XCD-chunked (grid 512 % 8 == 0): XCD k has fixed ctg=k (B tiles L2-hot).
  int s = (blockIdx.x & 7) * 64 + (blockIdx.x >> 3);
  int rt = s & 63, ctg = s >> 6;
  int tid = threadIdx.x, w = tid >> 6, l = tid & 63;
  int wr = (w >> 1) * 64, wc = (w & 1) * 64;
  int lo = l & 15, hi = l >> 4;
  // prologue: stage A + pos(8 tiles) + rT, then A -> registers
  stage_tile(f1b + (size_t)rt * 16384, Buf);
  __builtin_amdgcn_global_load_lds((as1u32*)(posw + ctg * 1024 + tid * 4),
                                   (as3u32*)(posS + tid * 4), 16, 0, 0);
  if (tid < 32)
    __builtin_amdgcn_global_load_lds((as1u32*)(rTw + rt * 128 + tid * 4),
                                     (as3u32*)(rS + tid * 4), 16, 0, 0);
  asm volatile("s_waitcnt vmcnt(0)" ::: "memory");
  __builtin_amdgcn_s_barrier();
  bf16x8 af[4][4];                       // [kk][m] A fragments in registers
  #pragma unroll
  for (int kk = 0; kk < 4; ++kk)
    #pragma unroll
    for (int m = 0; m < 4; ++m){
      int row = wr + m * 16 + lo;
      af[kk][m] = *(const bf16x8*)(Buf + row * 128 + ((kk * 4 + hi) ^ (row & 7)) * 8);
    }
  asm volatile("s_waitcnt lgkmcnt(0)" ::: "memory");
  __builtin_amdgcn_s_barrier();          // Buf free for B staging
  stage_tile(f2b + (size_t)(ctg * 8) * 16384, Buf);
  asm volatile("s_waitcnt vmcnt(0)" ::: "memory");
  __builtin_amdgcn_s_barrier();          // B(0) ready
  float pacc[4][4] = {{0.f,0.f,0.f,0.f},{0.f,0.f,0.f,0.f},{0.f,0.f,0.f,0.f},{0.f,0.f,0.f,0.f}};
  int prow = tid >> 5, pcol = (tid & 31) * 4;
  #pragma unroll 1
  for (int c8 = 0; c8 < 8; ++c8){
    int ct = ctg * 8 + c8;
    f32x4 acc[4][4];
    f32x4 zero = {0.f,0.f,0.f,0.f};
    #pragma unroll
    for (int m = 0; m < 4; ++m)
      #pragma unroll
      for (int n = 0; n < 4; ++n) acc[m][n] = zero;
    #pragma unroll
    for (int kk = 0; kk < 4; ++kk){
      bf16x8 bfv[4];
      #pragma unroll
      for (int n = 0; n < 4; ++n){
        int row = wc + n * 16 + lo;
        bfv[n] = *(const bf16x8*)(Buf + row * 128 + ((kk * 4 + hi) ^ (row & 7)) * 8);
      }
      #pragma unroll
      for (int m = 0; m < 4; ++m)
        #pragma unroll
        for (int n = 0; n < 4; ++n)
          acc[m][n] = __builtin_amdgcn_mfma_f32_16x16x32_bf16(af[kk][m], bfv[n], acc[m][n], 0, 0, 0);
    }
    asm volatile("s_waitcnt lgkmcnt(0)" ::: "memory");
    __builtin_amdgcn_s_barrier();        // all waves done reading Buf
    if (c8 < 7) stage_tile(f2b + (size_t)(ct + 1) * 16384, Buf);   // 8 loads, OLDEST
    __builtin_amdgcn_sched_barrier(0);   // pin: loads precede the stores below
    // epilogue for ct (pure reg/LDS + 16 nt-stores), overlaps the loads
    #pragma unroll
    for (int m = 0; m < 4; ++m)
      #pragma unroll
      for (int q = 0; q < 4; ++q){
        float r = rS[wr + m * 16 + hi * 4 + q];
        pacc[m][q] += __expf(acc[m][0][q] * r) + __expf(acc[m][1][q] * r)
                    + __expf(acc[m][2][q] * r) + __expf(acc[m][3][q] * r);
      }
    f32x4 p4 = *(const f32x4*)&posS[c8 * 128 + pcol];
    float* obase = out + (size_t)(rt * 128) * B_TOT + ct * 128 + pcol;
    #pragma unroll
    for (int pass = 0; pass < 16; ++pass){
      int row = pass * 8 + prow;
      float r = rS[row];
      f32x4 e;
      e.x = __expf(p4.x * r); e.y = __expf(p4.y * r);
      e.z = __expf(p4.z * r); e.w = __expf(p4.w * r);
      __builtin_nontemporal_store(e, (f32x4*)(obase + (size_t)row * B_TOT));
    }
    if (c8 < 7){
      // 8 loads are the oldest non-retired ops; 16 stores above are newest.
      asm volatile("s_waitcnt vmcnt(16)" ::: "memory");
      __builtin_amdgcn_s_barrier();      // B(c8+1) ready everywhere
    }
  }
  // tot partials: reduce across the 16 col-lanes, one atomic set per block
  #pragma unroll
  for (int m = 0; m < 4; ++m)
    #pragma unroll
    for (int q = 0; q < 4; ++q){
      float p = pacc[m][q];
      p += __shfl_xor(p, 1); p += __shfl_xor(p, 2);
      p += __shfl_xor(p, 4); p += __shfl_xor(p, 8);
      if (lo == 0) atomicAdd(out + OUT_TOT + rt * 128 + wr + m * 16 + hi * 4 + q, p);
    }
}

extern "C" void kernel_launch(void* const* d_in, const int* in_sizes, int n_in,
                              void* d_out, int out_size, void* d_ws, size_t ws_size,
                              hipStream_t stream){
  const float* x1 = (const float*)d_in[0];
  const float* x2 = (const float*)d_in[1];
  const int*   i1 = (const int*)d_in[2];
  const int*   i2 = (const int*)d_in[3];
  const float* W1 = (const float*)d_in[4];
  const float* b1 = (const float*)d_in[5];
  const float* W2 = (const float*)d_in[6];
  const float* b2 = (const float*)d_in[7];
  float* out = (float*)d_out;
  char* ws = (char*)d_ws;
  unsigned short* hb   = (unsigned short*)(ws);              // 2 MB
  unsigned short* f1b  = (unsigned short*)(ws + 2097152);    // 2 MB
  unsigned short* f2b  = (unsigned short*)(ws + 4194304);    // 2 MB
  float* posw  = (float*)(ws + 6291456);                     // 32 KB
  float* rTw   = (float*)(ws + 6324224);                     // 32 KB

  hipLaunchKernelGGL(k_feat,  dim3(8192), dim3(128), 0, stream, x1, x2, i1, i2, f1b, f2b, hb, posw, out);
  hipLaunchKernelGGL(k_lin,   dim3(64),   dim3(256), 0, stream, hb, W1, b1, W2, b2, rTw, out);
  hipLaunchKernelGGL(k_tot,   dim3(512),  dim3(256), 0, stream, f1b, f2b, rTw, posw, out);
}

// Round 8
// 87.410 us; speedup vs baseline: 1.0528x; 1.0528x over previous
//
#include <hip/hip_runtime.h>
#include <stdint.h>

typedef __bf16 bf16x8 __attribute__((ext_vector_type(8)));
typedef float f32x4 __attribute__((ext_vector_type(4)));
typedef __attribute__((address_space(3))) uint32_t as3u32;
typedef const __attribute__((address_space(1))) uint32_t as1u32;

#define B_TOT 8192
#define DD 128
#define OUT_TOT 67108864UL
#define OUT_AVG 67117056UL

__device__ inline unsigned short f2bf(float x){
  union { float f; uint32_t u; } v; v.f = x;
  return (unsigned short)((v.u + 0x7fffu + ((v.u >> 16) & 1u)) >> 16);
}

// ------- phase 1: gather + normalize + h + pos; one wave per sample ------------
__global__ __launch_bounds__(256) void k_feat(const float* __restrict__ x1,
    const float* __restrict__ x2, const int* __restrict__ i1a, const int* __restrict__ i2a,
    unsigned short* __restrict__ f1b, unsigned short* __restrict__ f2b,
    unsigned short* __restrict__ hb, float* __restrict__ posw, float* __restrict__ out){
  int tid = threadIdx.x;
  int gid = blockIdx.x * 256 + tid;
  if (gid <= 8192) out[OUT_TOT + gid] = 0.f;   // zero tot accum + avg slot
  int w = tid >> 6, l = tid & 63;
  int b = blockIdx.x * 4 + w;                  // grid 2048 -> b 0..8191
  const float2* r1 = (const float2*)(x1 + (size_t)i1a[b] * DD);
  const float2* r2 = (const float2*)(x2 + (size_t)i2a[b] * DD);
  float2 v1 = r1[l], v2 = r2[l];
  float s1 = v1.x * v1.x + v1.y * v1.y;
  float s2 = v2.x * v2.x + v2.y * v2.y;
  #pragma unroll
  for (int o = 32; o; o >>= 1){ s1 += __shfl_xor(s1, o); s2 += __shfl_xor(s2, o); }
  float inv1 = 1.f / fmaxf(sqrtf(s1), 1e-12f);
  float inv2 = 1.f / fmaxf(sqrtf(s2), 1e-12f);
  float f1x = v1.x * inv1, f1y = v1.y * inv1;
  float f2x = v2.x * inv2, f2y = v2.y * inv2;
  float hx = f1x * f2x, hy = f1y * f2y;
  float ps = hx + hy;
  #pragma unroll
  for (int o = 32; o; o >>= 1) ps += __shfl_xor(ps, o);
  unsigned int u1 = (unsigned int)f2bf(f1x) | ((unsigned int)f2bf(f1y) << 16);
  unsigned int u2 = (unsigned int)f2bf(f2x) | ((unsigned int)f2bf(f2y) << 16);
  unsigned int uh = (unsigned int)f2bf(hx)  | ((unsigned int)f2bf(hy)  << 16);
  ((unsigned int*)f1b)[b * 64 + l] = u1;
  ((unsigned int*)f2b)[b * 64 + l] = u2;
  ((unsigned int*)hb)[b * 64 + l]  = uh;
  if (l == 0) posw[b] = ps;
}

// ---------------- shared staging (128x128 bf16 tile, XOR-swizzled) ----------------
__device__ inline void stage_tile(const unsigned short* g, unsigned short* s){
  int tid = threadIdx.x;
  #pragma unroll
  for (int it = 0; it < 8; ++it){
    int c = tid + it * 256;          // 2048 chunks of 16B
    int row = c >> 4, cc = c & 15;
    int src = (row << 4) + (cc ^ (row & 7));
    __builtin_amdgcn_global_load_lds((as1u32*)(g + src * 8),
                                     (as3u32*)(s + c * 8), 16, 0, 0);
  }
}

// A-frag: row = lane&15, k = 8*(lane>>4)+e. C/D: col = lane&15, row=(lane>>4)*4+reg.
__device__ inline void mfma_tile(const unsigned short* As, const unsigned short* Bs,
                                 f32x4 acc[4][4]){
  int tid = threadIdx.x;
  int w = tid >> 6, l = tid & 63;
  int wr = (w >> 1) * 64, wc = (w & 1) * 64;
  int lo = l & 15, hi = l >> 4;
  f32x4 zero = {0.f, 0.f, 0.f, 0.f};
  #pragma unroll
  for (int m = 0; m < 4; ++m)
    #pragma unroll
    for (int n = 0; n < 4; ++n) acc[m][n] = zero;
  #pragma unroll
  for (int kk = 0; kk < 4; ++kk){
    bf16x8 af[4], bfv[4];
    #pragma unroll
    for (int m = 0; m < 4; ++m){
      int row = wr + m * 16 + lo;
      af[m] = *(const bf16x8*)(As + row * 128 + ((kk * 4 + hi) ^ (row & 7)) * 8);
    }
    #pragma unroll
    for (int n = 0; n < 4; ++n){
      int row = wc + n * 16 + lo;
      bfv[n] = *(const bf16x8*)(Bs + row * 128 + ((kk * 4 + hi) ^ (row & 7)) * 8);
    }
    #pragma unroll
    for (int m = 0; m < 4; ++m)
      #pragma unroll
      for (int n = 0; n < 4; ++n)
        acc[m][n] = __builtin_amdgcn_mfma_f32_16x16x32_bf16(af[m], bfv[n], acc[m][n], 0, 0, 0);
  }
}

// ---------------- phase 2: lin1 + leaky + lin2 + sigmoid -> rT, temp-mean -------
__global__ __launch_bounds__(256) void k_lin(const unsigned short* __restrict__ hb,
    const float* __restrict__ W1, const float* __restrict__ b1,
    const float* __restrict__ W2, const float* __restrict__ b2,
    float* __restrict__ rTw, float* __restrict__ out){
  __shared__ __align__(16) unsigned short As[16384];
  __shared__ __align__(16) unsigned short Bs[16384];
  __shared__ float zpart[2][128];
  __shared__ float s4[4];
  int i0 = blockIdx.x * 128;
  int tid = threadIdx.x;
  stage_tile(hb + (size_t)i0 * 128, As);
  #pragma unroll
  for (int it = 0; it < 8; ++it){
    int c = tid + it * 256;
    int row = c >> 4, cc = c & 15;
    int src = (row << 4) + (cc ^ (row & 7));
    const float4* g4 = (const float4*)(W1 + src * 8);
    float4 a = g4[0], b = g4[1];
    unsigned short t8[8];
    t8[0] = f2bf(a.x); t8[1] = f2bf(a.y); t8[2] = f2bf(a.z); t8[3] = f2bf(a.w);
    t8[4] = f2bf(b.x); t8[5] = f2bf(b.y); t8[6] = f2bf(b.z); t8[7] = f2bf(b.w);
    *(uint4*)(Bs + c * 8) = *(uint4*)t8;
  }
  asm volatile("s_waitcnt vmcnt(0)" ::: "memory");
  __syncthreads();
  f32x4 acc[4][4];
  mfma_tile(As, Bs, acc);
  int w = tid >> 6, l = tid & 63;
  int wrb = (w >> 1) * 64, wcb = (w & 1) * 64, lo = l & 15, hi = l >> 4;
  float w2v[4], b1v[4];
  #pragma unroll
  for (int n = 0; n < 4; ++n){ int col = wcb + n * 16 + lo; w2v[n] = W2[col]; b1v[n] = b1[col]; }
  #pragma unroll
  for (int m = 0; m < 4; ++m){
    #pragma unroll
    for (int q = 0; q < 4; ++q){
      float p = 0.f;
      #pragma unroll
      for (int n = 0; n < 4; ++n){
        float hv = acc[m][n][q] + b1v[n];
        hv = hv >= 0.f ? hv : 0.2f * hv;   // leaky_relu(0.2)
        p += hv * w2v[n];
      }
      p += __shfl_xor(p, 1); p += __shfl_xor(p, 2);
      p += __shfl_xor(p, 4); p += __shfl_xor(p, 8);
      if (lo == 0) zpart[w & 1][wrb + m * 16 + hi * 4 + q] = p;
    }
  }
  __syncthreads();
  float Tloc = 0.f;
  if (tid < 128){
    float z = zpart[0][tid] + zpart[1][tid] + b2[0];
    float s = 1.f / (1.f + __expf(-z));
    float T = 0.95f * (1.f - s) + 0.05f;
    rTw[i0 + tid] = 1.f / T;
    Tloc = T;
  }
  float v = Tloc;
  #pragma unroll
  for (int o = 32; o; o >>= 1) v += __shfl_xor(v, o);
  if ((tid & 63) == 0) s4[tid >> 6] = v;
  __syncthreads();
  if (tid == 0) atomicAdd(out + OUT_AVG, (s4[0] + s4[1] + s4[2] + s4[3]) * (1.0f / 8192.0f));
}

// ------- phase 3: tot GEMM + CONTIGUOUS-SLAB pos writer -------------------------
// GEMM mapping (rt,ctg) as before; pos_rating writes are decoupled: block s
// streams slab rows [s*16, s*16+16) -> per c8 iter, 2 whole rows = 64 KB of
// fully contiguous stores (fill-kernel-like DRAM pattern).
__global__ __launch_bounds__(256, 2) void k_tot(const unsigned short* __restrict__ f1b,
    const unsigned short* __restrict__ f2b, const float* __restrict__ rTw,
    const float* __restrict__ posw, float* __restrict__ out){
  __shared__ __align__(16) unsigned short Buf[16384];   // 32 KB
  __shared__ __align__(16) float posS[8192];            // 32 KB: full pos vector
  __shared__ __align__(16) float rS[128];               // rT for GEMM rows (rt)
  __shared__ __align__(16) float rQ[16];                // rT for slab rows
  int s = (blockIdx.x & 7) * 64 + (blockIdx.x >> 3);    // XCD-chunked, bijective
  int rt = s & 63, ctg = s >> 6;
  int tid = threadIdx.x, w = tid >> 6, l = tid & 63;
  int wr = (w >> 1) * 64, wc = (w & 1) * 64;
  int lo = l & 15, hi = l >> 4;
  // prologue staging: A tile, full posw, rT(rt rows), rT(slab rows)
  stage_tile(f1b + (size_t)rt * 16384, Buf);
  #pragma unroll
  for (int it = 0; it < 8; ++it){
    int c = tid + it * 256;        // 2048 chunks cover 8192 floats
    __builtin_amdgcn_global_load_lds((as1u32*)(posw + c * 4),
                                     (as3u32*)(posS + c * 4), 16, 0, 0);
  }
  if (tid < 32)
    __builtin_amdgcn_global_load_lds((as1u32*)(rTw + rt * 128 + tid * 4),
                                     (as3u32*)(rS + tid * 4), 16, 0, 0);
  if (tid < 4)
    __builtin_amdgcn_global_load_lds((as1u32*)(rTw + s * 16 + tid * 4),
                                     (as3u32*)(rQ + tid * 4), 16, 0, 0);
  asm volatile("s_waitcnt vmcnt(0)" ::: "memory");
  __builtin_amdgcn_s_barrier();
  bf16x8 af[4][4];                 // A fragments in registers
  #pragma unroll
  for (int kk = 0; kk < 4; ++kk)
    #pragma unroll
    for (int m = 0; m < 4; ++m){
      int row = wr + m * 16 + lo;
      af[kk][m] = *(const bf16x8*)(Buf + row * 128 + ((kk * 4 + hi) ^ (row & 7)) * 8);
    }
  asm volatile("s_waitcnt lgkmcnt(0)" ::: "memory");
  __builtin_amdgcn_s_barrier();    // Buf free for B staging
  stage_tile(f2b + (size_t)(ctg * 8) * 16384, Buf);
  asm volatile("s_waitcnt vmcnt(0)" ::: "memory");
  __builtin_amdgcn_s_barrier();    // B(0) ready
  float pacc[4][4] = {{0.f,0.f,0.f,0.f},{0.f,0.f,0.f,0.f},{0.f,0.f,0.f,0.f},{0.f,0.f,0.f,0.f}};
  // slab-store geometry: waves 0,1 -> row r0 (halves 0,1); waves 2,3 -> row r0+1
  int half = w & 1, rsel = w >> 1;
  #pragma unroll 1
  for (int c8 = 0; c8 < 8; ++c8){
    int ct = ctg * 8 + c8;
    f32x4 acc[4][4];
    f32x4 zero = {0.f,0.f,0.f,0.f};
    #pragma unroll
    for (int m = 0; m < 4; ++m)
      #pragma unroll
      for (int n = 0; n < 4; ++n) acc[m][n] = zero;
    #pragma unroll
    for (int kk = 0; kk < 4; ++kk){
      bf16x8 bfv[4];
      #pragma unroll
      for (int n = 0; n < 4; ++n){
        int row = wc + n * 16 + lo;
        bfv[n] = *(const bf16x8*)(Buf + row * 128 + ((kk * 4 + hi) ^ (row & 7)) * 8);
      }
      #pragma unroll
      for (int m = 0; m < 4; ++m)
        #pragma unroll
        for (int n = 0; n < 4; ++n)
          acc[m][n] = __builtin_amdgcn_mfma_f32_16x16x32_bf16(af[kk][m], bfv[n], acc[m][n], 0, 0, 0);
    }
    asm volatile("s_waitcnt lgkmcnt(0)" ::: "memory");
    __builtin_amdgcn_s_barrier();        // all waves done reading Buf
    if (c8 < 7) stage_tile(f2b + (size_t)(ct + 1) * 16384, Buf);   // 8 loads, OLDEST
    __builtin_amdgcn_sched_barrier(0);   // loads precede the stores below
    // tot accumulation for tile ct
    #pragma unroll
    for (int m = 0; m < 4; ++m)
      #pragma unroll
      for (int q = 0; q < 4; ++q){
        float r = rS[wr + m * 16 + hi * 4 + q];
        pacc[m][q] += __expf(acc[m][0][q] * r) + __expf(acc[m][1][q] * r)
                    + __expf(acc[m][2][q] * r) + __expf(acc[m][3][q] * r);
      }
    // slab writer: 2 contiguous rows (64 KB), 16 nt-stores/thread
    {
      int rowi = s * 16 + c8 * 2 + rsel;
      float rr = rQ[c8 * 2 + rsel];
      float* obase = out + (size_t)rowi * B_TOT + half * 4096;
      #pragma unroll
      for (int j = 0; j < 16; ++j){
        f32x4 p = *(const f32x4*)&posS[half * 4096 + j * 256 + l * 4];
        f32x4 e;
        e.x = __expf(p.x * rr); e.y = __expf(p.y * rr);
        e.z = __expf(p.z * rr); e.w = __expf(p.w * rr);
        __builtin_nontemporal_store(e, (f32x4*)(obase + j * 256 + l * 4));
      }
    }
    if (c8 < 7){
      asm volatile("s_waitcnt vmcnt(16)" ::: "memory");  // waits only the 8 loads
      __builtin_amdgcn_s_barrier();      // B(c8+1) ready everywhere
    }
  }
  // tot partials: reduce across the 16 col-lanes, one atomic set per block
  #pragma unroll
  for (int m = 0; m < 4; ++m)
    #pragma unroll
    for (int q = 0; q < 4; ++q){
      float p = pacc[m][q];
      p += __shfl_xor(p, 1); p += __shfl_xor(p, 2);
      p += __shfl_xor(p, 4); p += __shfl_xor(p, 8);
      if (lo == 0) atomicAdd(out + OUT_TOT + rt * 128 + wr + m * 16 + hi * 4 + q, p);
    }
}

extern "C" void kernel_launch(void* const* d_in, const int* in_sizes, int n_in,
                              void* d_out, int out_size, void* d_ws, size_t ws_size,
                              hipStream_t stream){
  const float* x1 = (const float*)d_in[0];
  const float* x2 = (const float*)d_in[1];
  const int*   i1 = (const int*)d_in[2];
  const int*   i2 = (const int*)d_in[3];
  const float* W1 = (const float*)d_in[4];
  const float* b1 = (const float*)d_in[5];
  const float* W2 = (const float*)d_in[6];
  const float* b2 = (const float*)d_in[7];
  float* out = (float*)d_out;
  char* ws = (char*)d_ws;
  unsigned short* hb   = (unsigned short*)(ws);              // 2 MB
  unsigned short* f1b  = (unsigned short*)(ws + 2097152);    // 2 MB
  unsigned short* f2b  = (unsigned short*)(ws + 4194304);    // 2 MB
  float* posw  = (float*)(ws + 6291456);                     // 32 KB
  float* rTw   = (float*)(ws + 6324224);                     // 32 KB

  hipLaunchKernelGGL(k_feat,  dim3(2048), dim3(256), 0, stream, x1, x2, i1, i2, f1b, f2b, hb, posw, out);
  hipLaunchKernelGGL(k_lin,   dim3(64),   dim3(256), 0, stream, hb, W1, b1, W2, b2, rTw, out);
  hipLaunchKernelGGL(k_tot,   dim3(512),  dim3(256), 0, stream, f1b, f2b, rTw, posw, out);
}

// Round 9
// 86.557 us; speedup vs baseline: 1.0631x; 1.0098x over previous
//
#include <hip/hip_runtime.h>
#include <stdint.h>

typedef __bf16 bf16x8 __attribute__((ext_vector_type(8)));
typedef float f32x4 __attribute__((ext_vector_type(4)));
typedef __attribute__((address_space(3))) uint32_t as3u32;
typedef const __attribute__((address_space(1))) uint32_t as1u32;

#define B_TOT 8192
#define DD 128
#define OUT_TOT 67108864UL
#define OUT_AVG 67117056UL

__device__ inline unsigned short f2bf(float x){
  union { float f; uint32_t u; } v; v.f = x;
  return (unsigned short)((v.u + 0x7fffu + ((v.u >> 16) & 1u)) >> 16);
}

// ------- phase 1: gather + normalize + h + pos; one wave per sample ------------
__global__ __launch_bounds__(256) void k_feat(const float* __restrict__ x1,
    const float* __restrict__ x2, const int* __restrict__ i1a, const int* __restrict__ i2a,
    unsigned short* __restrict__ f1b, unsigned short* __restrict__ f2b,
    unsigned short* __restrict__ hb, float* __restrict__ posw, float* __restrict__ out){
  int tid = threadIdx.x;
  int gid = blockIdx.x * 256 + tid;
  if (gid <= 8192) out[OUT_TOT + gid] = 0.f;   // zero tot accum + avg slot
  int w = tid >> 6, l = tid & 63;
  int b = blockIdx.x * 4 + w;                  // grid 2048 -> b 0..8191
  const float2* r1 = (const float2*)(x1 + (size_t)i1a[b] * DD);
  const float2* r2 = (const float2*)(x2 + (size_t)i2a[b] * DD);
  float2 v1 = r1[l], v2 = r2[l];
  float s1 = v1.x * v1.x + v1.y * v1.y;
  float s2 = v2.x * v2.x + v2.y * v2.y;
  #pragma unroll
  for (int o = 32; o; o >>= 1){ s1 += __shfl_xor(s1, o); s2 += __shfl_xor(s2, o); }
  float inv1 = 1.f / fmaxf(sqrtf(s1), 1e-12f);
  float inv2 = 1.f / fmaxf(sqrtf(s2), 1e-12f);
  float f1x = v1.x * inv1, f1y = v1.y * inv1;
  float f2x = v2.x * inv2, f2y = v2.y * inv2;
  float hx = f1x * f2x, hy = f1y * f2y;
  float ps = hx + hy;
  #pragma unroll
  for (int o = 32; o; o >>= 1) ps += __shfl_xor(ps, o);
  unsigned int u1 = (unsigned int)f2bf(f1x) | ((unsigned int)f2bf(f1y) << 16);
  unsigned int u2 = (unsigned int)f2bf(f2x) | ((unsigned int)f2bf(f2y) << 16);
  unsigned int uh = (unsigned int)f2bf(hx)  | ((unsigned int)f2bf(hy)  << 16);
  ((unsigned int*)f1b)[b * 64 + l] = u1;
  ((unsigned int*)f2b)[b * 64 + l] = u2;
  ((unsigned int*)hb)[b * 64 + l]  = uh;
  if (l == 0) posw[b] = ps;
}

// ---------------- shared staging (128x128 bf16 tile, XOR-swizzled) ----------------
__device__ inline void stage_tile(const unsigned short* g, unsigned short* s){
  int tid = threadIdx.x;
  #pragma unroll
  for (int it = 0; it < 8; ++it){
    int c = tid + it * 256;          // 2048 chunks of 16B
    int row = c >> 4, cc = c & 15;
    int src = (row << 4) + (cc ^ (row & 7));
    __builtin_amdgcn_global_load_lds((as1u32*)(g + src * 8),
                                     (as3u32*)(s + c * 8), 16, 0, 0);
  }
}

// A-frag: row = lane&15, k = 8*(lane>>4)+e. C/D: col = lane&15, row=(lane>>4)*4+reg.
__device__ inline void mfma_tile(const unsigned short* As, const unsigned short* Bs,
                                 f32x4 acc[4][4]){
  int tid = threadIdx.x;
  int w = tid >> 6, l = tid & 63;
  int wr = (w >> 1) * 64, wc = (w & 1) * 64;
  int lo = l & 15, hi = l >> 4;
  f32x4 zero = {0.f, 0.f, 0.f, 0.f};
  #pragma unroll
  for (int m = 0; m < 4; ++m)
    #pragma unroll
    for (int n = 0; n < 4; ++n) acc[m][n] = zero;
  #pragma unroll
  for (int kk = 0; kk < 4; ++kk){
    bf16x8 af[4], bfv[4];
    #pragma unroll
    for (int m = 0; m < 4; ++m){
      int row = wr + m * 16 + lo;
      af[m] = *(const bf16x8*)(As + row * 128 + ((kk * 4 + hi) ^ (row & 7)) * 8);
    }
    #pragma unroll
    for (int n = 0; n < 4; ++n){
      int row = wc + n * 16 + lo;
      bfv[n] = *(const bf16x8*)(Bs + row * 128 + ((kk * 4 + hi) ^ (row & 7)) * 8);
    }
    #pragma unroll
    for (int m = 0; m < 4; ++m)
      #pragma unroll
      for (int n = 0; n < 4; ++n)
        acc[m][n] = __builtin_amdgcn_mfma_f32_16x16x32_bf16(af[m], bfv[n], acc[m][n], 0, 0, 0);
  }
}

// ---------------- phase 2: lin1 + leaky + lin2 + sigmoid -> rT, temp-mean -------
__global__ __launch_bounds__(256) void k_lin(const unsigned short* __restrict__ hb,
    const float* __restrict__ W1, const float* __restrict__ b1,
    const float* __restrict__ W2, const float* __restrict__ b2,
    float* __restrict__ rTw, float* __restrict__ out){
  __shared__ __align__(16) unsigned short As[16384];
  __shared__ __align__(16) unsigned short Bs[16384];
  __shared__ float zpart[2][128];
  __shared__ float s4[4];
  int i0 = blockIdx.x * 128;
  int tid = threadIdx.x;
  stage_tile(hb + (size_t)i0 * 128, As);
  #pragma unroll
  for (int it = 0; it < 8; ++it){
    int c = tid + it * 256;
    int row = c >> 4, cc = c & 15;
    int src = (row << 4) + (cc ^ (row & 7));
    const float4* g4 = (const float4*)(W1 + src * 8);
    float4 a = g4[0], b = g4[1];
    unsigned short t8[8];
    t8[0] = f2bf(a.x); t8[1] = f2bf(a.y); t8[2] = f2bf(a.z); t8[3] = f2bf(a.w);
    t8[4] = f2bf(b.x); t8[5] = f2bf(b.y); t8[6] = f2bf(b.z); t8[7] = f2bf(b.w);
    *(uint4*)(Bs + c * 8) = *(uint4*)t8;
  }
  asm volatile("s_waitcnt vmcnt(0)" ::: "memory");
  __syncthreads();
  f32x4 acc[4][4];
  mfma_tile(As, Bs, acc);
  int w = tid >> 6, l = tid & 63;
  int wrb = (w >> 1) * 64, wcb = (w & 1) * 64, lo = l & 15, hi = l >> 4;
  float w2v[4], b1v[4];
  #pragma unroll
  for (int n = 0; n < 4; ++n){ int col = wcb + n * 16 + lo; w2v[n] = W2[col]; b1v[n] = b1[col]; }
  #pragma unroll
  for (int m = 0; m < 4; ++m){
    #pragma unroll
    for (int q = 0; q < 4; ++q){
      float p = 0.f;
      #pragma unroll
      for (int n = 0; n < 4; ++n){
        float hv = acc[m][n][q] + b1v[n];
        hv = hv >= 0.f ? hv : 0.2f * hv;   // leaky_relu(0.2)
        p += hv * w2v[n];
      }
      p += __shfl_xor(p, 1); p += __shfl_xor(p, 2);
      p += __shfl_xor(p, 4); p += __shfl_xor(p, 8);
      if (lo == 0) zpart[w & 1][wrb + m * 16 + hi * 4 + q] = p;
    }
  }
  __syncthreads();
  float Tloc = 0.f;
  if (tid < 128){
    float z = zpart[0][tid] + zpart[1][tid] + b2[0];
    float s = 1.f / (1.f + __expf(-z));
    float T = 0.95f * (1.f - s) + 0.05f;
    rTw[i0 + tid] = 1.f / T;
    Tloc = T;
  }
  float v = Tloc;
  #pragma unroll
  for (int o = 32; o; o >>= 1) v += __shfl_xor(v, o);
  if ((tid & 63) == 0) s4[tid >> 6] = v;
  __syncthreads();
  if (tid == 0) atomicAdd(out + OUT_AVG, (s4[0] + s4[1] + s4[2] + s4[3]) * (1.0f / 8192.0f));
}

// ------- phase 3: tot GEMM only (A in regs, B looped through LDS) ---------------
__global__ __launch_bounds__(256, 2) void k_tot(const unsigned short* __restrict__ f1b,
    const unsigned short* __restrict__ f2b, const float* __restrict__ rTw,
    float* __restrict__ out){
  __shared__ __align__(16) unsigned short Buf[16384];   // 32 KB
  __shared__ __align__(16) float rS[128];
  int s = (blockIdx.x & 7) * 64 + (blockIdx.x >> 3);    // XCD-chunked, bijective
  int rt = s & 63, ctg = s >> 6;
  int tid = threadIdx.x, w = tid >> 6, l = tid & 63;
  int wr = (w >> 1) * 64, wc = (w & 1) * 64;
  int lo = l & 15, hi = l >> 4;
  stage_tile(f1b + (size_t)rt * 16384, Buf);
  if (tid < 32)
    __builtin_amdgcn_global_load_lds((as1u32*)(rTw + rt * 128 + tid * 4),
                                     (as3u32*)(rS + tid * 4), 16, 0, 0);
  asm volatile("s_waitcnt vmcnt(0)" ::: "memory");
  __builtin_amdgcn_s_barrier();
  bf16x8 af[4][4];                 // A fragments in registers
  #pragma unroll
  for (int kk = 0; kk < 4; ++kk)
    #pragma unroll
    for (int m = 0; m < 4; ++m){
      int row = wr + m * 16 + lo;
      af[kk][m] = *(const bf16x8*)(Buf + row * 128 + ((kk * 4 + hi) ^ (row & 7)) * 8);
    }
  asm volatile("s_waitcnt lgkmcnt(0)" ::: "memory");
  __builtin_amdgcn_s_barrier();    // Buf free for B staging
  stage_tile(f2b + (size_t)(ctg * 8) * 16384, Buf);
  asm volatile("s_waitcnt vmcnt(0)" ::: "memory");
  __builtin_amdgcn_s_barrier();    // B(0) ready
  float pacc[4][4] = {{0.f,0.f,0.f,0.f},{0.f,0.f,0.f,0.f},{0.f,0.f,0.f,0.f},{0.f,0.f,0.f,0.f}};
  #pragma unroll 1
  for (int c8 = 0; c8 < 8; ++c8){
    int ct = ctg * 8 + c8;
    f32x4 acc[4][4];
    f32x4 zero = {0.f,0.f,0.f,0.f};
    #pragma unroll
    for (int m = 0; m < 4; ++m)
      #pragma unroll
      for (int n = 0; n < 4; ++n) acc[m][n] = zero;
    #pragma unroll
    for (int kk = 0; kk < 4; ++kk){
      bf16x8 bfv[4];
      #pragma unroll
      for (int n = 0; n < 4; ++n){
        int row = wc + n * 16 + lo;
        bfv[n] = *(const bf16x8*)(Buf + row * 128 + ((kk * 4 + hi) ^ (row & 7)) * 8);
      }
      #pragma unroll
      for (int m = 0; m < 4; ++m)
        #pragma unroll
        for (int n = 0; n < 4; ++n)
          acc[m][n] = __builtin_amdgcn_mfma_f32_16x16x32_bf16(af[kk][m], bfv[n], acc[m][n], 0, 0, 0);
    }
    asm volatile("s_waitcnt lgkmcnt(0)" ::: "memory");
    __builtin_amdgcn_s_barrier();        // all waves done reading Buf
    if (c8 < 7) stage_tile(f2b + (size_t)(ct + 1) * 16384, Buf);   // prefetch next
    // exp accumulation overlaps the in-flight loads
    #pragma unroll
    for (int m = 0; m < 4; ++m)
      #pragma unroll
      for (int q = 0; q < 4; ++q){
        float r = rS[wr + m * 16 + hi * 4 + q];
        pacc[m][q] += __expf(acc[m][0][q] * r) + __expf(acc[m][1][q] * r)
                    + __expf(acc[m][2][q] * r) + __expf(acc[m][3][q] * r);
      }
    if (c8 < 7){
      asm volatile("s_waitcnt vmcnt(0)" ::: "memory");
      __builtin_amdgcn_s_barrier();      // B(c8+1) ready
    }
  }
  // tot partials: reduce across the 16 col-lanes, one atomic set per block
  #pragma unroll
  for (int m = 0; m < 4; ++m)
    #pragma unroll
    for (int q = 0; q < 4; ++q){
      float p = pacc[m][q];
      p += __shfl_xor(p, 1); p += __shfl_xor(p, 2);
      p += __shfl_xor(p, 4); p += __shfl_xor(p, 8);
      if (lo == 0) atomicAdd(out + OUT_TOT + rt * 128 + wr + m * 16 + hi * 4 + q, p);
    }
}

// ------- phase 4: pos_rating writer, fill-kernel-shaped ------------------------
// 2048 blocks x 256 threads; block bid writes rows [4*bid, 4*bid+4) = one
// contiguous 128 KB slab. pos chunks cached in 32 VGPRs, reused across 4 rows.
// Plain (L2-path) stores, exactly like the 6.8 TB/s fill kernel.
__global__ __launch_bounds__(256) void k_pr(const float* __restrict__ posw,
    const float* __restrict__ rTw, float* __restrict__ out){
  int tid = threadIdx.x;
  int r0 = blockIdx.x * 4;
  f32x4 p[8];
  #pragma unroll
  for (int c = 0; c < 8; ++c) p[c] = *(const f32x4*)(posw + (c * 256 + tid) * 4);
  float4 rr4 = *(const float4*)(rTw + r0);
  float rr[4] = {rr4.x, rr4.y, rr4.z, rr4.w};
  #pragma unroll
  for (int r = 0; r < 4; ++r){
    float* ob = out + (size_t)(r0 + r) * B_TOT;
    #pragma unroll
    for (int c = 0; c < 8; ++c){
      f32x4 e;
      e.x = __expf(p[c].x * rr[r]); e.y = __expf(p[c].y * rr[r]);
      e.z = __expf(p[c].z * rr[r]); e.w = __expf(p[c].w * rr[r]);
      *(f32x4*)(ob + (c * 256 + tid) * 4) = e;
    }
  }
}

extern "C" void kernel_launch(void* const* d_in, const int* in_sizes, int n_in,
                              void* d_out, int out_size, void* d_ws, size_t ws_size,
                              hipStream_t stream){
  const float* x1 = (const float*)d_in[0];
  const float* x2 = (const float*)d_in[1];
  const int*   i1 = (const int*)d_in[2];
  const int*   i2 = (const int*)d_in[3];
  const float* W1 = (const float*)d_in[4];
  const float* b1 = (const float*)d_in[5];
  const float* W2 = (const float*)d_in[6];
  const float* b2 = (const float*)d_in[7];
  float* out = (float*)d_out;
  char* ws = (char*)d_ws;
  unsigned short* hb   = (unsigned short*)(ws);              // 2 MB
  unsigned short* f1b  = (unsigned short*)(ws + 2097152);    // 2 MB
  unsigned short* f2b  = (unsigned short*)(ws + 4194304);    // 2 MB
  float* posw  = (float*)(ws + 6291456);                     // 32 KB
  float* rTw   = (float*)(ws + 6324224);                     // 32 KB

  hipLaunchKernelGGL(k_feat,  dim3(2048), dim3(256), 0, stream, x1, x2, i1, i2, f1b, f2b, hb, posw, out);
  hipLaunchKernelGGL(k_lin,   dim3(64),   dim3(256), 0, stream, hb, W1, b1, W2, b2, rTw, out);
  hipLaunchKernelGGL(k_tot,   dim3(512),  dim3(256), 0, stream, f1b, f2b, rTw, out);
  hipLaunchKernelGGL(k_pr,    dim3(2048), dim3(256), 0, stream, posw, rTw, out);
}

// Round 10
// 85.921 us; speedup vs baseline: 1.0710x; 1.0074x over previous
//
#include <hip/hip_runtime.h>
#include <stdint.h>

typedef __bf16 bf16x8 __attribute__((ext_vector_type(8)));
typedef float f32x4 __attribute__((ext_vector_type(4)));
typedef __attribute__((address_space(3))) uint32_t as3u32;
typedef const __attribute__((address_space(1))) uint32_t as1u32;

#define B_TOT 8192
#define DD 128
#define OUT_TOT 67108864UL
#define OUT_AVG 67117056UL

__device__ inline unsigned short f2bf(float x){
  union { float f; uint32_t u; } v; v.f = x;
  return (unsigned short)((v.u + 0x7fffu + ((v.u >> 16) & 1u)) >> 16);
}

// ------- phase 1: gather + normalize + h + pos; one wave per sample ------------
__global__ __launch_bounds__(256) void k_feat(const float* __restrict__ x1,
    const float* __restrict__ x2, const int* __restrict__ i1a, const int* __restrict__ i2a,
    unsigned short* __restrict__ f1b, unsigned short* __restrict__ f2b,
    unsigned short* __restrict__ hb, float* __restrict__ posw, float* __restrict__ out){
  int tid = threadIdx.x;
  int gid = blockIdx.x * 256 + tid;
  if (gid <= 8192) out[OUT_TOT + gid] = 0.f;   // zero tot accum + avg slot
  int w = tid >> 6, l = tid & 63;
  int b = blockIdx.x * 4 + w;                  // grid 2048 -> b 0..8191
  const float2* r1 = (const float2*)(x1 + (size_t)i1a[b] * DD);
  const float2* r2 = (const float2*)(x2 + (size_t)i2a[b] * DD);
  float2 v1 = r1[l], v2 = r2[l];
  float s1 = v1.x * v1.x + v1.y * v1.y;
  float s2 = v2.x * v2.x + v2.y * v2.y;
  #pragma unroll
  for (int o = 32; o; o >>= 1){ s1 += __shfl_xor(s1, o); s2 += __shfl_xor(s2, o); }
  float inv1 = 1.f / fmaxf(sqrtf(s1), 1e-12f);
  float inv2 = 1.f / fmaxf(sqrtf(s2), 1e-12f);
  float f1x = v1.x * inv1, f1y = v1.y * inv1;
  float f2x = v2.x * inv2, f2y = v2.y * inv2;
  float hx = f1x * f2x, hy = f1y * f2y;
  float ps = hx + hy;
  #pragma unroll
  for (int o = 32; o; o >>= 1) ps += __shfl_xor(ps, o);
  unsigned int u1 = (unsigned int)f2bf(f1x) | ((unsigned int)f2bf(f1y) << 16);
  unsigned int u2 = (unsigned int)f2bf(f2x) | ((unsigned int)f2bf(f2y) << 16);
  unsigned int uh = (unsigned int)f2bf(hx)  | ((unsigned int)f2bf(hy)  << 16);
  ((unsigned int*)f1b)[b * 64 + l] = u1;
  ((unsigned int*)f2b)[b * 64 + l] = u2;
  ((unsigned int*)hb)[b * 64 + l]  = uh;
  if (l == 0) posw[b] = ps;
}

// ---------------- shared staging (128x128 bf16 tile, XOR-swizzled) ----------------
__device__ inline void stage_tile(const unsigned short* g, unsigned short* s){
  int tid = threadIdx.x;
  #pragma unroll
  for (int it = 0; it < 8; ++it){
    int c = tid + it * 256;          // 2048 chunks of 16B
    int row = c >> 4, cc = c & 15;
    int src = (row << 4) + (cc ^ (row & 7));
    __builtin_amdgcn_global_load_lds((as1u32*)(g + src * 8),
                                     (as3u32*)(s + c * 8), 16, 0, 0);
  }
}

// A-frag: row = lane&15, k = 8*(lane>>4)+e. C/D: col = lane&15, row=(lane>>4)*4+reg.
__device__ inline void mfma_tile(const unsigned short* As, const unsigned short* Bs,
                                 f32x4 acc[4][4]){
  int tid = threadIdx.x;
  int w = tid >> 6, l = tid & 63;
  int wr = (w >> 1) * 64, wc = (w & 1) * 64;
  int lo = l & 15, hi = l >> 4;
  f32x4 zero = {0.f, 0.f, 0.f, 0.f};
  #pragma unroll
  for (int m = 0; m < 4; ++m)
    #pragma unroll
    for (int n = 0; n < 4; ++n) acc[m][n] = zero;
  #pragma unroll
  for (int kk = 0; kk < 4; ++kk){
    bf16x8 af[4], bfv[4];
    #pragma unroll
    for (int m = 0; m < 4; ++m){
      int row = wr + m * 16 + lo;
      af[m] = *(const bf16x8*)(As + row * 128 + ((kk * 4 + hi) ^ (row & 7)) * 8);
    }
    #pragma unroll
    for (int n = 0; n < 4; ++n){
      int row = wc + n * 16 + lo;
      bfv[n] = *(const bf16x8*)(Bs + row * 128 + ((kk * 4 + hi) ^ (row & 7)) * 8);
    }
    #pragma unroll
    for (int m = 0; m < 4; ++m)
      #pragma unroll
      for (int n = 0; n < 4; ++n)
        acc[m][n] = __builtin_amdgcn_mfma_f32_16x16x32_bf16(af[m], bfv[n], acc[m][n], 0, 0, 0);
  }
}

// ---------------- phase 2: lin1 + leaky + lin2 + sigmoid -> rT, temp-mean -------
__global__ __launch_bounds__(256) void k_lin(const unsigned short* __restrict__ hb,
    const float* __restrict__ W1, const float* __restrict__ b1,
    const float* __restrict__ W2, const float* __restrict__ b2,
    float* __restrict__ rTw, float* __restrict__ out){
  __shared__ __align__(16) unsigned short As[16384];
  __shared__ __align__(16) unsigned short Bs[16384];
  __shared__ float zpart[2][128];
  __shared__ float s4[4];
  int i0 = blockIdx.x * 128;
  int tid = threadIdx.x;
  stage_tile(hb + (size_t)i0 * 128, As);
  #pragma unroll
  for (int it = 0; it < 8; ++it){
    int c = tid + it * 256;
    int row = c >> 4, cc = c & 15;
    int src = (row << 4) + (cc ^ (row & 7));
    const float4* g4 = (const float4*)(W1 + src * 8);
    float4 a = g4[0], b = g4[1];
    unsigned short t8[8];
    t8[0] = f2bf(a.x); t8[1] = f2bf(a.y); t8[2] = f2bf(a.z); t8[3] = f2bf(a.w);
    t8[4] = f2bf(b.x); t8[5] = f2bf(b.y); t8[6] = f2bf(b.z); t8[7] = f2bf(b.w);
    *(uint4*)(Bs + c * 8) = *(uint4*)t8;
  }
  asm volatile("s_waitcnt vmcnt(0)" ::: "memory");
  __syncthreads();
  f32x4 acc[4][4];
  mfma_tile(As, Bs, acc);
  int w = tid >> 6, l = tid & 63;
  int wrb = (w >> 1) * 64, wcb = (w & 1) * 64, lo = l & 15, hi = l >> 4;
  float w2v[4], b1v[4];
  #pragma unroll
  for (int n = 0; n < 4; ++n){ int col = wcb + n * 16 + lo; w2v[n] = W2[col]; b1v[n] = b1[col]; }
  #pragma unroll
  for (int m = 0; m < 4; ++m){
    #pragma unroll
    for (int q = 0; q < 4; ++q){
      float p = 0.f;
      #pragma unroll
      for (int n = 0; n < 4; ++n){
        float hv = acc[m][n][q] + b1v[n];
        hv = hv >= 0.f ? hv : 0.2f * hv;   // leaky_relu(0.2)
        p += hv * w2v[n];
      }
      p += __shfl_xor(p, 1); p += __shfl_xor(p, 2);
      p += __shfl_xor(p, 4); p += __shfl_xor(p, 8);
      if (lo == 0) zpart[w & 1][wrb + m * 16 + hi * 4 + q] = p;
    }
  }
  __syncthreads();
  float Tloc = 0.f;
  if (tid < 128){
    float z = zpart[0][tid] + zpart[1][tid] + b2[0];
    float s = 1.f / (1.f + __expf(-z));
    float T = 0.95f * (1.f - s) + 0.05f;
    rTw[i0 + tid] = 1.f / T;
    Tloc = T;
  }
  float v = Tloc;
  #pragma unroll
  for (int o = 32; o; o >>= 1) v += __shfl_xor(v, o);
  if ((tid & 63) == 0) s4[tid >> 6] = v;
  __syncthreads();
  if (tid == 0) atomicAdd(out + OUT_AVG, (s4[0] + s4[1] + s4[2] + s4[3]) * (1.0f / 8192.0f));
}

// ------- phase 3: block-specialized fused kernel -------------------------------
// Grid 2560. bid%5==2 -> GEMM role (512 blocks, = R9 k_tot); else writer role
// (2048 blocks, = R9 k_pr). Writers keep the HBM write pipe saturated for the
// whole kernel; GEMM rides on MFMA + L2 reads underneath.
__global__ __launch_bounds__(256) void k_main(const unsigned short* __restrict__ f1b,
    const unsigned short* __restrict__ f2b, const float* __restrict__ rTw,
    const float* __restrict__ posw, float* __restrict__ out){
  __shared__ __align__(16) unsigned short Buf[16384];   // 32 KB (GEMM role only)
  __shared__ __align__(16) float rS[128];
  int bid = blockIdx.x;
  int tid = threadIdx.x;
  if (bid % 5 == 2){
    // ---------------- GEMM role ----------------
    int g = bid / 5;
    int s = (g & 7) * 64 + (g >> 3);    // XCD-chunked, bijective (512 % 8 == 0)
    int rt = s & 63, ctg = s >> 6;
    int w = tid >> 6, l = tid & 63;
    int wr = (w >> 1) * 64, wc = (w & 1) * 64;
    int lo = l & 15, hi = l >> 4;
    stage_tile(f1b + (size_t)rt * 16384, Buf);
    if (tid < 32)
      __builtin_amdgcn_global_load_lds((as1u32*)(rTw + rt * 128 + tid * 4),
                                       (as3u32*)(rS + tid * 4), 16, 0, 0);
    asm volatile("s_waitcnt vmcnt(0)" ::: "memory");
    __builtin_amdgcn_s_barrier();
    bf16x8 af[4][4];                 // A fragments in registers
    #pragma unroll
    for (int kk = 0; kk < 4; ++kk)
      #pragma unroll
      for (int m = 0; m < 4; ++m){
        int row = wr + m * 16 + lo;
        af[kk][m] = *(const bf16x8*)(Buf + row * 128 + ((kk * 4 + hi) ^ (row & 7)) * 8);
      }
    asm volatile("s_waitcnt lgkmcnt(0)" ::: "memory");
    __builtin_amdgcn_s_barrier();    // Buf free for B staging
    stage_tile(f2b + (size_t)(ctg * 8) * 16384, Buf);
    asm volatile("s_waitcnt vmcnt(0)" ::: "memory");
    __builtin_amdgcn_s_barrier();    // B(0) ready
    float pacc[4][4] = {{0.f,0.f,0.f,0.f},{0.f,0.f,0.f,0.f},{0.f,0.f,0.f,0.f},{0.f,0.f,0.f,0.f}};
    #pragma unroll 1
    for (int c8 = 0; c8 < 8; ++c8){
      int ct = ctg * 8 + c8;
      f32x4 acc[4][4];
      f32x4 zero = {0.f,0.f,0.f,0.f};
      #pragma unroll
      for (int m = 0; m < 4; ++m)
        #pragma unroll
        for (int n = 0; n < 4; ++n) acc[m][n] = zero;
      #pragma unroll
      for (int kk = 0; kk < 4; ++kk){
        bf16x8 bfv[4];
        #pragma unroll
        for (int n = 0; n < 4; ++n){
          int row = wc + n * 16 + lo;
          bfv[n] = *(const bf16x8*)(Buf + row * 128 + ((kk * 4 + hi) ^ (row & 7)) * 8);
        }
        #pragma unroll
        for (int m = 0; m < 4; ++m)
          #pragma unroll
          for (int n = 0; n < 4; ++n)
            acc[m][n] = __builtin_amdgcn_mfma_f32_16x16x32_bf16(af[kk][m], bfv[n], acc[m][n], 0, 0, 0);
      }
      asm volatile("s_waitcnt lgkmcnt(0)" ::: "memory");
      __builtin_amdgcn_s_barrier();        // all waves done reading Buf
      if (c8 < 7) stage_tile(f2b + (size_t)(ct + 1) * 16384, Buf);   // prefetch next
      #pragma unroll
      for (int m = 0; m < 4; ++m)
        #pragma unroll
        for (int q = 0; q < 4; ++q){
          float r = rS[wr + m * 16 + hi * 4 + q];
          pacc[m][q] += __expf(acc[m][0][q] * r) + __expf(acc[m][1][q] * r)
                      + __expf(acc[m][2][q] * r) + __expf(acc[m][3][q] * r);
        }
      if (c8 < 7){
        asm volatile("s_waitcnt vmcnt(0)" ::: "memory");
        __builtin_amdgcn_s_barrier();      // B(c8+1) ready
      }
    }
    #pragma unroll
    for (int m = 0; m < 4; ++m)
      #pragma unroll
      for (int q = 0; q < 4; ++q){
        float p = pacc[m][q];
        p += __shfl_xor(p, 1); p += __shfl_xor(p, 2);
        p += __shfl_xor(p, 4); p += __shfl_xor(p, 8);
        if (lo == 0) atomicAdd(out + OUT_TOT + rt * 128 + wr + m * 16 + hi * 4 + q, p);
      }
  } else {
    // ---------------- writer role ----------------
    int wid = bid - bid / 5 - ((bid % 5) > 2 ? 1 : 0);   // 0..2047, bijective
    int r0 = wid * 4;
    f32x4 p[8];
    #pragma unroll
    for (int c = 0; c < 8; ++c) p[c] = *(const f32x4*)(posw + (c * 256 + tid) * 4);
    float4 rr4 = *(const float4*)(rTw + r0);
    float rr[4] = {rr4.x, rr4.y, rr4.z, rr4.w};
    #pragma unroll
    for (int r = 0; r < 4; ++r){
      float* ob = out + (size_t)(r0 + r) * B_TOT;
      #pragma unroll
      for (int c = 0; c < 8; ++c){
        f32x4 e;
        e.x = __expf(p[c].x * rr[r]); e.y = __expf(p[c].y * rr[r]);
        e.z = __expf(p[c].z * rr[r]); e.w = __expf(p[c].w * rr[r]);
        *(f32x4*)(ob + (c * 256 + tid) * 4) = e;
      }
    }
  }
}

extern "C" void kernel_launch(void* const* d_in, const int* in_sizes, int n_in,
                              void* d_out, int out_size, void* d_ws, size_t ws_size,
                              hipStream_t stream){
  const float* x1 = (const float*)d_in[0];
  const float* x2 = (const float*)d_in[1];
  const int*   i1 = (const int*)d_in[2];
  const int*   i2 = (const int*)d_in[3];
  const float* W1 = (const float*)d_in[4];
  const float* b1 = (const float*)d_in[5];
  const float* W2 = (const float*)d_in[6];
  const float* b2 = (const float*)d_in[7];
  float* out = (float*)d_out;
  char* ws = (char*)d_ws;
  unsigned short* hb   = (unsigned short*)(ws);              // 2 MB
  unsigned short* f1b  = (unsigned short*)(ws + 2097152);    // 2 MB
  unsigned short* f2b  = (unsigned short*)(ws + 4194304);    // 2 MB
  float* posw  = (float*)(ws + 6291456);                     // 32 KB
  float* rTw   = (float*)(ws + 6324224);                     // 32 KB

  hipLaunchKernelGGL(k_feat, dim3(2048), dim3(256), 0, stream, x1, x2, i1, i2, f1b, f2b, hb, posw, out);
  hipLaunchKernelGGL(k_lin,  dim3(64),   dim3(256), 0, stream, hb, W1, b1, W2, b2, rTw, out);
  hipLaunchKernelGGL(k_main, dim3(2560), dim3(256), 0, stream, f1b, f2b, rTw, posw, out);
}